// Round 2
// baseline (275.787 us; speedup 1.0000x reference)
//
#include <hip/hip_runtime.h>
#include <math.h>

// out[m, n] = base[n] - pre_cls[n, idx[m]],  base[n] = sum_c softplus(pre_cls[n, c])
// M = N = 8192, C = 80.
// Strategy: precompute D[c][n] = base[n] - pre_cls[n, c] (2.6 MB, L2-resident),
// then out row m is a contiguous copy of D row idx[m]  -> pure HBM-write-bound.
//
// R1 changes vs 285 µs baseline (R2 = identical resubmit; R1 bench hit
// GPUAcquisitionTimeout twice and was never measured):
//  - ce_gather: 1 block per row, 8 float4 per thread (was 1), idx load amortized.
//  - nontemporal stores for out (write-only stream; keeps D resident in L2).
//  - ce_prep: 4 threads per n (shuffle-reduced), pre values kept in regs for pass 2.

#define CE_C 80

typedef float v4f __attribute__((ext_vector_type(4)));

__device__ __forceinline__ float softplus_f(float x) {
    // logaddexp(x, 0) = max(x,0) + log1p(exp(-|x|))
    return fmaxf(x, 0.0f) + log1pf(expf(-fabsf(x)));
}

// 4 threads per n; block of 256 covers 64 n's. Each part handles 20 classes (5 float4s).
__global__ __launch_bounds__(256) void ce_prep(const float* __restrict__ pre,
                                               float* __restrict__ D, int N) {
    int t = threadIdx.x;
    int n = blockIdx.x * 64 + (t >> 2);
    if (n >= N) return;
    int part = t & 3;                       // c in [part*20, part*20+20)
    const float* row = pre + (long)n * CE_C + part * 20;   // 16B-aligned (80B steps)
    v4f v[5];
    float s = 0.0f;
#pragma unroll
    for (int j = 0; j < 5; ++j) {
        v[j] = *reinterpret_cast<const v4f*>(row + j * 4);
        s += softplus_f(v[j].x) + softplus_f(v[j].y)
           + softplus_f(v[j].z) + softplus_f(v[j].w);
    }
    // reduce across the 4-lane group (lanes are consecutive)
    s += __shfl_xor(s, 1);
    s += __shfl_xor(s, 2);
    int c0 = part * 20;
#pragma unroll
    for (int j = 0; j < 5; ++j) {
        float* d0 = D + (long)(c0 + j * 4) * N + n;
        d0[0]           = s - v[j].x;
        d0[(long)N]     = s - v[j].y;
        d0[2 * (long)N] = s - v[j].z;
        d0[3 * (long)N] = s - v[j].w;
    }
}

// One block per output row. Each of 256 threads copies 8 float4s (32 KB/row).
// Loads batched before stores; stores are nontemporal (out is never re-read).
__global__ __launch_bounds__(256) void ce_gather(const float* __restrict__ D,
                                                 const int* __restrict__ idx,
                                                 float* __restrict__ out, int N) {
    int m = blockIdx.x;
    int c = idx[m];                          // wave-uniform -> scalar load
    const v4f* __restrict__ src = reinterpret_cast<const v4f*>(D + (long)c * N);
    v4f* __restrict__ dst = reinterpret_cast<v4f*>(out + (long)m * N);
    int t = threadIdx.x;
    int nvec = N >> 2;
    if (nvec == 2048) {                      // fast path: N == 8192
        v4f v[8];
#pragma unroll
        for (int k = 0; k < 8; ++k) v[k] = src[t + k * 256];
#pragma unroll
        for (int k = 0; k < 8; ++k) __builtin_nontemporal_store(v[k], &dst[t + k * 256]);
    } else {
        for (int i = t; i < nvec; i += 256)
            __builtin_nontemporal_store(src[i], &dst[i]);
    }
}

// ---- fallback path (workspace too small for D): base only (32 KB) ----
__global__ void ce_base(const float* __restrict__ pre, float* __restrict__ base, int N) {
    int n = blockIdx.x * blockDim.x + threadIdx.x;
    if (n >= N) return;
    const float* row = pre + (long)n * CE_C;
    float b = 0.0f;
#pragma unroll
    for (int c = 0; c < CE_C; c += 4) {
        v4f v = *reinterpret_cast<const v4f*>(row + c);
        b += softplus_f(v.x);
        b += softplus_f(v.y);
        b += softplus_f(v.z);
        b += softplus_f(v.w);
    }
    base[n] = b;
}

__global__ void ce_direct(const float* __restrict__ pre, const float* __restrict__ base,
                          const int* __restrict__ idx, float* __restrict__ out, int N) {
    int m = blockIdx.x;
    int c = idx[m];
    int n0 = (blockIdx.y * blockDim.x + threadIdx.x) * 4;
    if (n0 >= N) return;
    v4f b = *reinterpret_cast<const v4f*>(base + n0);
    v4f r;
    r.x = b.x - pre[(long)(n0 + 0) * CE_C + c];
    r.y = b.y - pre[(long)(n0 + 1) * CE_C + c];
    r.z = b.z - pre[(long)(n0 + 2) * CE_C + c];
    r.w = b.w - pre[(long)(n0 + 3) * CE_C + c];
    *reinterpret_cast<v4f*>(out + (long)m * N + n0) = r;
}

extern "C" void kernel_launch(void* const* d_in, const int* in_sizes, int n_in,
                              void* d_out, int out_size, void* d_ws, size_t ws_size,
                              hipStream_t stream) {
    const int* idx  = (const int*)d_in[0];     // gt_kind_ind, int32 [M]
    const float* pre = (const float*)d_in[1];  // pre_cls, f32 [N, C]
    float* out = (float*)d_out;                // f32 [M, N]

    const int M = in_sizes[0];
    const int N = in_sizes[1] / CE_C;

    const size_t needD = (size_t)CE_C * (size_t)N * sizeof(float);
    const int block = 256;

    if (ws_size >= needD) {
        float* D = (float*)d_ws;
        ce_prep<<<(N + 63) / 64, block, 0, stream>>>(pre, D, N);
        ce_gather<<<M, block, 0, stream>>>(D, idx, out, N);
    } else {
        const int chunks = (N + 4 * block - 1) / (4 * block);   // 8 for N=8192
        float* base = (float*)d_ws;            // N floats
        ce_base<<<(N + block - 1) / block, block, 0, stream>>>(pre, base, N);
        dim3 grid(M, chunks);
        ce_direct<<<grid, block, 0, stream>>>(pre, base, idx, out, N);
    }
}